// Round 15
// baseline (593.792 us; speedup 1.0000x reference)
//
#include <hip/hip_runtime.h>
#include <cstdint>
#include <cstddef>

// Problem constants
#define B_  256
#define S_  128
#define D_  1024
#define H_  8
#define DH_ 128
#define M_  (B_ * S_)   // 32768 rows

typedef _Float16 half8 __attribute__((ext_vector_type(8)));
typedef float    f32x4 __attribute__((ext_vector_type(4)));

#define GLOAD_LDS16(gp, lp)                                                    \
    __builtin_amdgcn_global_load_lds(                                          \
        (const __attribute__((address_space(1))) void*)(gp),                   \
        (__attribute__((address_space(3))) void*)(lp), 16, 0, 0)

// ---------------------------------------------------------------------------
// ROUND 15: single merged conversion kernel (was 3 launches).
// units: [0, NA)               : code f32 -> codeh f16 (half8 units)
//        [NA, NA+NB)           : Wq/Wk/Wv -> Wt (B^T f16) + bias_all
//        [NA+NB, NA+NB+NC)     : Wo -> Wot (B^T f16)
// ---------------------------------------------------------------------------
#define NA_ (M_ * 1024 / 8)        // 4,194,304
#define NB_ (3072 * 128)           //   393,216
#define NC_ (1024 * 256)           //   262,144

__global__ __launch_bounds__(256)
void cvt_all(const float* __restrict__ code,
             const float* __restrict__ Wq, const float* __restrict__ Wk,
             const float* __restrict__ Wv,
             const float* __restrict__ bq, const float* __restrict__ bk,
             const float* __restrict__ bv, const float* __restrict__ Wo,
             _Float16* __restrict__ codeh, _Float16* __restrict__ Wt,
             float* __restrict__ bias_all, _Float16* __restrict__ Wot)
{
    int u = blockIdx.x * 256 + threadIdx.x;
    if (u < NA_) {
        const float4* s = (const float4*)code;
        float4 a = s[2 * u], b = s[2 * u + 1];
        half8 o;
        o[0] = (_Float16)a.x; o[1] = (_Float16)a.y; o[2] = (_Float16)a.z; o[3] = (_Float16)a.w;
        o[4] = (_Float16)b.x; o[5] = (_Float16)b.y; o[6] = (_Float16)b.z; o[7] = (_Float16)b.w;
        *(half8*)(codeh + (size_t)u * 8) = o;
        return;
    }
    u -= NA_;
    if (u < NB_) {
        int n = u >> 7, kc = u & 127, k = kc * 8;
        int qkv = n >> 10, hf = n & 1023, h = hf >> 7, f = hf & 127;
        const float* W = (qkv == 0 ? Wq : (qkv == 1 ? Wk : Wv))
                         + (size_t)h * D_ * DH_ + (size_t)k * DH_ + f;
        half8 o;
        #pragma unroll
        for (int j = 0; j < 8; ++j) o[j] = (_Float16)W[(size_t)j * DH_];
        *(half8*)(Wt + (size_t)n * 1024 + k) = o;
        if (kc == 0)
            bias_all[n] = (qkv == 0 ? bq : (qkv == 1 ? bk : bv))[h * DH_ + f];
        return;
    }
    u -= NB_;
    if (u < NC_) {
        int n = u >> 8, kc = u & 255, k = kc * 8;
        const float* W = Wo + (size_t)k * 1024 + n;
        half8 o;
        #pragma unroll
        for (int j = 0; j < 8; ++j) o[j] = (_Float16)W[(size_t)j * 1024];
        *(half8*)(Wot + (size_t)n * 2048 + k) = o;
    }
}

// ---------------------------------------------------------------------------
// 256x256 f16 MFMA GEMM, full-tile-prefetch schedule (Round-8 exact — the
// best-measured variant across R5-R14: ~230 us proj, MfmaUtil ~39%).
// One publication point per K-tile: vmcnt(0)+barrier at tile head (loads
// issued one full tile ago -> free), stage all of t+1, compute 4 quadrants
// with no mid-tile publication waits, one mid-tile sched fence.
// ---------------------------------------------------------------------------
template <bool OUTF32>
__global__ __launch_bounds__(512, 1)
void gemm_f16_8p(const _Float16* __restrict__ A1p, const _Float16* __restrict__ A2p,
                 int K1, const _Float16* __restrict__ Bt,
                 const float* __restrict__ bias, void* __restrict__ outp,
                 int Ntot, int Ktot, int ntn)
{
    __shared__ __align__(16) char lds[131072];

    const int tid = threadIdx.x;
    const int w = tid >> 6, l = tid & 63;
    const int wm = w >> 2, wn = w & 3;
    const int lr = l & 15, lg = l >> 4;

    const int cpx = gridDim.x >> 3;
    const int bid = blockIdx.x;
    const int swz = (bid & 7) * cpx + (bid >> 3);
    const int m0 = (swz / ntn) * 256, n0 = (swz % ntn) * 256;

    const int NT = Ktot >> 6;

    const int srow  = l >> 3;
    const int sgcol = ((l & 7) ^ srow) * 8;

    auto stageHalf = [&](int bufi, int t, int half) {
        const int k0 = t << 6;
        const bool isA = (half == 0) || (half == 3);
        const int hh = (half >= 2) ? 1 : 0;
        char* dst0 = lds + bufi * 65536 + (isA ? 0 : 32768) + hh * 16384;
        if (isA) {
            const _Float16* Asrc; int kc;
            if (k0 < K1) { Asrc = A1p; kc = k0; } else { Asrc = A2p; kc = k0 - K1; }
            #pragma unroll
            for (int i = 0; i < 2; ++i) {
                const int c = i * 8 + w;
                const int row = hh * 128 + c * 8 + srow;
                const _Float16* g = Asrc + (size_t)(m0 + row) * 1024 + kc + sgcol;
                GLOAD_LDS16(g, dst0 + c * 1024);
            }
        } else {
            #pragma unroll
            for (int i = 0; i < 2; ++i) {
                const int c = i * 8 + w;
                const int row = hh * 128 + c * 8 + srow;
                const _Float16* g = Bt + (size_t)(n0 + row) * Ktot + k0 + sgcol;
                GLOAD_LDS16(g, dst0 + c * 1024);
            }
        }
    };

    auto ldA = [&](int bufi, int fi, int ks) -> half8 {
        const int row = fi * 32 + wm * 16 + lr;
        const int pos = (ks * 4 + lg) ^ (row & 7);
        return *(const half8*)(lds + bufi * 65536 + row * 128 + pos * 16);
    };
    auto ldB = [&](int bufi, int fj, int ks) -> half8 {
        const int row = fj * 64 + wn * 16 + lr;
        const int pos = (ks * 4 + lg) ^ (row & 7);
        return *(const half8*)(lds + bufi * 65536 + 32768 + row * 128 + pos * 16);
    };

    f32x4 acc[8][4] = {};
    half8 aq[4][2], b0[2][2], b1[2][2];

    stageHalf(0, 0, 0); stageHalf(0, 0, 1); stageHalf(0, 0, 2); stageHalf(0, 0, 3);

    for (int t = 0; t < NT; ++t) {
        const int buf = t & 1;
        const bool nl = (t + 1 < NT);

        asm volatile("s_waitcnt vmcnt(0)" ::: "memory");
        __builtin_amdgcn_s_barrier();

        if (nl) {
            stageHalf(buf ^ 1, t + 1, 0); stageHalf(buf ^ 1, t + 1, 1);
            stageHalf(buf ^ 1, t + 1, 2); stageHalf(buf ^ 1, t + 1, 3);
        }

        #pragma unroll
        for (int fi = 0; fi < 4; ++fi)
            #pragma unroll
            for (int ks = 0; ks < 2; ++ks)
                aq[fi][ks] = ldA(buf, fi, ks);
        #pragma unroll
        for (int fj = 0; fj < 2; ++fj)
            #pragma unroll
            for (int ks = 0; ks < 2; ++ks)
                b0[fj][ks] = ldB(buf, fj, ks);
        #pragma unroll
        for (int fj = 0; fj < 2; ++fj)
            #pragma unroll
            for (int ks = 0; ks < 2; ++ks)
                b1[fj][ks] = ldB(buf, fj + 2, ks);

        __builtin_amdgcn_s_setprio(1);
        #pragma unroll
        for (int ks = 0; ks < 2; ++ks)
            #pragma unroll
            for (int fi = 0; fi < 4; ++fi)
                #pragma unroll
                for (int fj = 0; fj < 2; ++fj)
                    acc[fi][fj] = __builtin_amdgcn_mfma_f32_16x16x32_f16(
                        aq[fi][ks], b0[fj][ks], acc[fi][fj], 0, 0, 0);
        #pragma unroll
        for (int ks = 0; ks < 2; ++ks)
            #pragma unroll
            for (int fi = 0; fi < 4; ++fi)
                #pragma unroll
                for (int fj = 0; fj < 2; ++fj)
                    acc[fi][fj + 2] = __builtin_amdgcn_mfma_f32_16x16x32_f16(
                        aq[fi][ks], b1[fj][ks], acc[fi][fj + 2], 0, 0, 0);
        __builtin_amdgcn_s_setprio(0);

        __builtin_amdgcn_s_barrier();

        #pragma unroll
        for (int fi = 0; fi < 4; ++fi)
            #pragma unroll
            for (int ks = 0; ks < 2; ++ks)
                aq[fi][ks] = ldA(buf, fi + 4, ks);

        __builtin_amdgcn_s_setprio(1);
        #pragma unroll
        for (int ks = 0; ks < 2; ++ks)
            #pragma unroll
            for (int fi = 0; fi < 4; ++fi)
                #pragma unroll
                for (int fj = 0; fj < 2; ++fj)
                    acc[fi + 4][fj + 2] = __builtin_amdgcn_mfma_f32_16x16x32_f16(
                        aq[fi][ks], b1[fj][ks], acc[fi + 4][fj + 2], 0, 0, 0);
        #pragma unroll
        for (int ks = 0; ks < 2; ++ks)
            #pragma unroll
            for (int fi = 0; fi < 4; ++fi)
                #pragma unroll
                for (int fj = 0; fj < 2; ++fj)
                    acc[fi + 4][fj] = __builtin_amdgcn_mfma_f32_16x16x32_f16(
                        aq[fi][ks], b0[fj][ks], acc[fi + 4][fj], 0, 0, 0);
        __builtin_amdgcn_s_setprio(0);
    }

    #pragma unroll
    for (int fi = 0; fi < 8; ++fi) {
        #pragma unroll
        for (int fj = 0; fj < 4; ++fj) {
            const int n = n0 + fj * 64 + wn * 16 + lr;
            const float bs = bias[n];
            #pragma unroll
            for (int rg = 0; rg < 4; ++rg) {
                const int m = m0 + fi * 32 + wm * 16 + lg * 4 + rg;
                float v = acc[fi][fj][rg] + bs;
                v = v > 0.0f ? v : 0.0f;
                if constexpr (OUTF32)
                    ((float*)outp)[(size_t)m * Ntot + n] = v;
                else
                    ((_Float16*)outp)[(size_t)m * Ntot + n] = (_Float16)v;
            }
        }
    }
}

// ---------------------------------------------------------------------------
// Attention (Round-9 structure; passed 3x, kept frozen).
// ---------------------------------------------------------------------------
__global__ __launch_bounds__(256, 2)
void attn_pdg_mfma(const _Float16* __restrict__ QKV, const float* __restrict__ Rel,
                   _Float16* __restrict__ resh)
{
    __shared__ __align__(16) char smem[75776];
    unsigned* rbits = (unsigned*)(smem + 70656);
    float* rowpart  = (float*)(smem + 72704);
    float* colpart  = (float*)(smem + 73728);
    float* inv_in   = (float*)(smem + 74752);
    float* inv_out  = (float*)(smem + 75264);

    const int tid = threadIdx.x;
    const int w = tid >> 6, l = tid & 63;
    const int wr = w >> 1, wc = w & 1;
    const int lr = l & 15, lg = l >> 4;
    const int h = blockIdx.x, b = blockIdx.y;

    for (int s = w; s < S_; s += 4) {
        const float* row = &Rel[((size_t)b * S_ + s) * S_];
        unsigned long long b0m = __ballot(row[l] > 0.5f);
        unsigned long long b1m = __ballot(row[64 + l] > 0.5f);
        if (l == 0) {
            rbits[s * 4 + 0] = (unsigned)b0m; rbits[s * 4 + 1] = (unsigned)(b0m >> 32);
            rbits[s * 4 + 2] = (unsigned)b1m; rbits[s * 4 + 3] = (unsigned)(b1m >> 32);
        }
    }

    const size_t gbase = (size_t)(b * S_) * 3072 + h * DH_;

    const _Float16* Vb = QKV + gbase + 2048;
    const int vrow = tid >> 1, vcol0 = (tid & 1) * 64;
    uint4 vreg[8];
    #pragma unroll
    for (int j = 0; j < 8; ++j)
        vreg[j] = *(const uint4*)&Vb[(size_t)vrow * 3072 + vcol0 + j * 8];

    #pragma unroll
    for (int i = 0; i < 8; ++i) {
        const int row = (w * 8 + i) * 4 + (l >> 4);
        const int gsrc = (l & 15) ^ (row & 7);
        const _Float16* gq = QKV + gbase + (size_t)row * 3072 + gsrc * 8;
        GLOAD_LDS16(gq, smem + (w * 8 + i) * 1024);
        const _Float16* gk = QKV + gbase + 1024 + (size_t)row * 3072 + gsrc * 8;
        GLOAD_LDS16(gk, smem + 32768 + (w * 8 + i) * 1024);
    }
    __syncthreads();

    f32x4 acc[4][4] = {};
    #pragma unroll
    for (int kc = 0; kc < 4; ++kc) {
        half8 af[4], bf[4];
        #pragma unroll
        for (int i = 0; i < 4; ++i) {
            const int row = wr * 64 + i * 16 + lr;
            const int pos = (kc * 4 + lg) ^ (row & 7);
            af[i] = *(const half8*)(smem + row * 256 + pos * 16);
        }
        #pragma unroll
        for (int j = 0; j < 4; ++j) {
            const int row = wc * 64 + j * 16 + lr;
            const int pos = (kc * 4 + lg) ^ (row & 7);
            bf[j] = *(const half8*)(smem + 32768 + row * 256 + pos * 16);
        }
        #pragma unroll
        for (int i = 0; i < 4; ++i)
            #pragma unroll
            for (int j = 0; j < 4; ++j)
                acc[i][j] = __builtin_amdgcn_mfma_f32_16x16x32_f16(af[i], bf[j], acc[i][j], 0, 0, 0);
    }

    auto relf = [&](int s, int t) -> float {
        float r;
        if (h < H_ / 2) {
            r = (float)((rbits[s * 4 + (t >> 5)] >> (t & 31)) & 1u);
            if (s == t) r += (float)h;
        } else {
            r = (float)((rbits[t * 4 + (s >> 5)] >> (s & 31)) & 1u);
        }
        return r;
    };

    f32x4 p[4][4];
    #pragma unroll
    for (int i = 0; i < 4; ++i)
        #pragma unroll
        for (int j = 0; j < 4; ++j)
            #pragma unroll
            for (int rg = 0; rg < 4; ++rg) {
                const int s = wr * 64 + i * 16 + lg * 4 + rg;
                const int t = wc * 64 + j * 16 + lr;
                p[i][j][rg] = relf(s, t) * acc[i][j][rg] + 1e-11f;
            }

    #pragma unroll
    for (int i = 0; i < 4; ++i)
        #pragma unroll
        for (int rg = 0; rg < 4; ++rg) {
            float part = p[i][0][rg] + p[i][1][rg] + p[i][2][rg] + p[i][3][rg];
            part += __shfl_xor(part, 1);
            part += __shfl_xor(part, 2);
            part += __shfl_xor(part, 4);
            part += __shfl_xor(part, 8);
            if (lr == 0) rowpart[wc * 128 + wr * 64 + i * 16 + lg * 4 + rg] = part;
        }
    #pragma unroll
    for (int j = 0; j < 4; ++j) {
        float part = 0.0f;
        #pragma unroll
        for (int i = 0; i < 4; ++i)
            part += p[i][j][0] + p[i][j][1] + p[i][j][2] + p[i][j][3];
        part += __shfl_xor(part, 16);
        part += __shfl_xor(part, 32);
        if (lg == 0) colpart[wr * 128 + wc * 64 + j * 16 + lr] = part;
    }
    __syncthreads();

    if (tid < 128) {
        inv_in[tid] = rsqrtf(colpart[tid] + colpart[128 + tid]);
    } else {
        const int s = tid - 128;
        inv_out[s] = rsqrtf(rowpart[s] + rowpart[128 + s]);
    }
    __syncthreads();

    float itj[4];
    #pragma unroll
    for (int j = 0; j < 4; ++j) itj[j] = inv_in[wc * 64 + j * 16 + lr];
    #pragma unroll
    for (int i = 0; i < 4; ++i)
        #pragma unroll
        for (int rg = 0; rg < 4; ++rg) {
            const int s = wr * 64 + i * 16 + lg * 4 + rg;
            const float os = inv_out[s];
            #pragma unroll
            for (int j = 0; j < 4; ++j) {
                const int t = wc * 64 + j * 16 + lr;
                const float val = relf(s, t) * p[i][j][rg] * itj[j] * os;
                *(_Float16*)(smem + s * 272 + t * 2) = (_Float16)val;
            }
        }

    #pragma unroll
    for (int j = 0; j < 8; ++j) {
        union { uint4 u; _Float16 hh[8]; } uu;
        uu.u = vreg[j];
        #pragma unroll
        for (int e = 0; e < 8; ++e) {
            const int f = vcol0 + j * 8 + e;
            *(_Float16*)(smem + 34816 + f * 280 + vrow * 2) = uu.hh[e];
        }
    }
    __syncthreads();

    f32x4 acc2[4][4] = {};
    #pragma unroll
    for (int kc = 0; kc < 4; ++kc) {
        half8 af[4], bf[4];
        #pragma unroll
        for (int i = 0; i < 4; ++i)
            af[i] = *(const half8*)(smem + (wr * 64 + i * 16 + lr) * 272 + kc * 64 + lg * 16);
        #pragma unroll
        for (int j = 0; j < 4; ++j)
            bf[j] = *(const half8*)(smem + 34816 + (wc * 64 + j * 16 + lr) * 280 + kc * 64 + lg * 16);
        #pragma unroll
        for (int i = 0; i < 4; ++i)
            #pragma unroll
            for (int j = 0; j < 4; ++j)
                acc2[i][j] = __builtin_amdgcn_mfma_f32_16x16x32_f16(af[i], bf[j], acc2[i][j], 0, 0, 0);
    }

    #pragma unroll
    for (int i = 0; i < 4; ++i)
        #pragma unroll
        for (int rg = 0; rg < 4; ++rg) {
            const int s = wr * 64 + i * 16 + lg * 4 + rg;
            #pragma unroll
            for (int j = 0; j < 4; ++j) {
                const int f = wc * 64 + j * 16 + lr;
                resh[((size_t)(b * S_ + s)) * 1024 + h * DH_ + f] = (_Float16)acc2[i][j][rg];
            }
        }
}

// ---------------------------------------------------------------------------
extern "C" void kernel_launch(void* const* d_in, const int* in_sizes, int n_in,
                              void* d_out, int out_size, void* d_ws, size_t ws_size,
                              hipStream_t stream)
{
    const float* code = (const float*)d_in[0];
    const float* Rel  = (const float*)d_in[1];
    const float* Wq   = (const float*)d_in[2];
    const float* bq   = (const float*)d_in[3];
    const float* Wk   = (const float*)d_in[4];
    const float* bk   = (const float*)d_in[5];
    const float* Wv   = (const float*)d_in[6];
    const float* bv   = (const float*)d_in[7];
    const float* Wo   = (const float*)d_in[8];
    const float* bo   = (const float*)d_in[9];
    float* out = (float*)d_out;
    (void)in_sizes; (void)n_in; (void)out_size; (void)ws_size;

    char* wsp = (char*)d_ws;
    _Float16* codeh = (_Float16*)wsp;  wsp += (size_t)M_ * 1024 * 2;
    _Float16* QKV   = (_Float16*)wsp;  wsp += (size_t)M_ * 3072 * 2;
    _Float16* resh  = (_Float16*)wsp;  wsp += (size_t)M_ * 1024 * 2;
    _Float16* Wt    = (_Float16*)wsp;  wsp += (size_t)3072 * 1024 * 2;
    _Float16* Wot   = (_Float16*)wsp;  wsp += (size_t)1024 * 2048 * 2;
    float* bias_all = (float*)wsp;     wsp += 3072 * 4;

    const int ncvt = (NA_ + NB_ + NC_ + 255) / 256;
    cvt_all<<<ncvt, 256, 0, stream>>>(code, Wq, Wk, Wv, bq, bk, bv, Wo,
                                      codeh, Wt, bias_all, Wot);

    // QKV projection: [M,1024] x [1024,3072] -> QKV f16 [M][3072]
    gemm_f16_8p<false><<<(M_ / 256) * (3072 / 256), 512, 0, stream>>>(
        codeh, codeh, 1024, Wt, bias_all, (void*)QKV, 3072, 1024, 3072 / 256);

    attn_pdg_mfma<<<dim3(H_, B_), 256, 0, stream>>>(QKV, Rel, resh);

    // Output projection: [M, 2048(=resh|codeh)] x [2048,1024] -> out f32
    gemm_f16_8p<true><<<(M_ / 256) * (1024 / 256), 512, 0, stream>>>(
        resh, codeh, 1024, Wot, bo, (void*)out, 1024, 2048, 1024 / 256);
}